// Round 7
// baseline (463.930 us; speedup 1.0000x reference)
//
#include <hip/hip_runtime.h>

// Monarch block-diag: out[b, s*64+l] = sum_r w2[l,s,r] * sum_p x[b, r*64+p] * w1[r,l,p]
// B=8192, N=4096, blocks 64. fp32 in/out; bf16 MFMA compute.
//
// R7 = R6 resubmit (r6 bench was an infra container failure; kernel audited: no OOB,
// layouts re-derived, regs <= 128, all acc indices compile-time).
//
// Structure (lane-owns-granule): r0-r5 established that a 256-B out granule
// (= out[b][s*64..+64], all 64 l) avoids write amplification ONLY if produced by one
// wave within a tight window (r4: single-instruction granules -> 1.07x ideal WRITE;
// r5: granule split across 4 waves -> 1.85x). This version makes each LANE own a full
// granule in registers:
//   stage-2 swaps MFMA operands (A = w2 with M=s, B = Y with N=b, 4 real b dup x4);
//   wave = (s-tile st, b-half bh); lane keeps D[row = quad*4 + (m>>2)][col = m] for
//   its (b = bh*4+(m&3), s = st*16+quad*4+(m>>2)); acc2[64] over all l = the granule;
//   epilogue = 16 back-to-back dwordx4 stores per lane -> L2 merges to full lines.
// Block: 512 thr (8 waves), b-tile 8, grid 1024, Y = 64 KiB LDS only, ONE barrier,
// __launch_bounds__(512,4) -> 2 blocks/CU so block A's store drain overlaps block B's
// x-load/compute (r4's 1-block/CU phase serialization capped BW at 2.1 TB/s).

typedef __bf16 bf16x8 __attribute__((ext_vector_type(8)));
typedef float  float4v __attribute__((ext_vector_type(4)));

__global__ __launch_bounds__(256)
void cvt_weights(const float* __restrict__ w1, const float* __restrict__ w2,
                 __bf16* __restrict__ wb) {
    const int i = (blockIdx.x * 256 + threadIdx.x) * 8;  // grid 128 -> i < 262144
    float4v a = *(const float4v*)(w1 + i);
    float4v b = *(const float4v*)(w1 + i + 4);
    bf16x8 v;
    v[0]=(__bf16)a[0]; v[1]=(__bf16)a[1]; v[2]=(__bf16)a[2]; v[3]=(__bf16)a[3];
    v[4]=(__bf16)b[0]; v[5]=(__bf16)b[1]; v[6]=(__bf16)b[2]; v[7]=(__bf16)b[3];
    *(bf16x8*)(wb + i) = v;
    a = *(const float4v*)(w2 + i);
    b = *(const float4v*)(w2 + i + 4);
    v[0]=(__bf16)a[0]; v[1]=(__bf16)a[1]; v[2]=(__bf16)a[2]; v[3]=(__bf16)a[3];
    v[4]=(__bf16)b[0]; v[5]=(__bf16)b[1]; v[6]=(__bf16)b[2]; v[7]=(__bf16)b[3];
    *(bf16x8*)(wb + 262144 + i) = v;
}

__global__ __launch_bounds__(512, 4)
void monarch_fused(const float* __restrict__ x,
                   const __bf16* __restrict__ w1b,
                   const __bf16* __restrict__ w2b,
                   float* __restrict__ out)
{
    // Y: [bl(8)][q(64)][kchunk(8) xor-swz][elem(8)] bf16 = 64 KiB dynamic LDS.
    // Swizzle cs = kchunk ^ (q&7) ^ (bl&7) (r5-proven write pattern).
    extern __shared__ __align__(16) unsigned char smem[];
    __bf16* Y = (__bf16*)smem;

    const int tid  = threadIdx.x;
    const int wid  = tid >> 6;      // 0..7
    const int lane = tid & 63;
    const int m    = lane & 15;
    const int quad = lane >> 4;
    const int b0   = blockIdx.x * 8;
    const int brow = m & 7;         // stage-1 real b-row (A rows 8..15 duplicate)

    // ---- stage-1: wave = k-chunk kw; preload x A-frags (k = kw*8+j, p = h*32+quad*8+e)
    const int kw = wid;
    bf16x8 xa[8][2];
    {
        const float* xp = x + (long)(b0 + brow) * 4096 + kw * 512 + quad * 8;
        #pragma unroll
        for (int j = 0; j < 8; ++j) {
            #pragma unroll
            for (int h = 0; h < 2; ++h) {
                float4v lo = *(const float4v*)(xp + j * 64 + h * 32);
                float4v hi = *(const float4v*)(xp + j * 64 + h * 32 + 4);
                bf16x8 v;
                v[0]=(__bf16)lo[0]; v[1]=(__bf16)lo[1]; v[2]=(__bf16)lo[2]; v[3]=(__bf16)lo[3];
                v[4]=(__bf16)hi[0]; v[5]=(__bf16)hi[1]; v[6]=(__bf16)hi[2]; v[7]=(__bf16)hi[3];
                xa[j][h] = v;
            }
        }
    }

    // ---- stage-1 compute: Y[b][q][k] for k in [kw*8,+8), all 64 q (4 tiles) ----
    #pragma unroll
    for (int qt = 0; qt < 4; ++qt) {
        float4v acc[8];
        #pragma unroll
        for (int j = 0; j < 8; ++j) {
            const int k = kw * 8 + j;
            const __bf16* w1p = w1b + ((k * 64 + qt * 16 + m) * 64) + quad * 8;
            bf16x8 bb0 = *(const bf16x8*)(w1p);
            bf16x8 bb1 = *(const bf16x8*)(w1p + 32);
            float4v c = {0.f, 0.f, 0.f, 0.f};
            c = __builtin_amdgcn_mfma_f32_16x16x32_bf16(xa[j][0], bb0, c, 0, 0, 0);
            c = __builtin_amdgcn_mfma_f32_16x16x32_bf16(xa[j][1], bb1, c, 0, 0, 0);
            acc[j] = c;
        }
        // D: lane holds D[b = quad*4+reg][q = qt*16+m]; rows >=8 are duplicates -> skip.
        if (quad < 2) {
            #pragma unroll
            for (int reg = 0; reg < 4; ++reg) {
                const int bl = quad * 4 + reg;        // 0..7
                const int q  = qt * 16 + m;
                const int cs = kw ^ (m & 7) ^ (bl & 7);
                bf16x8 v;
                #pragma unroll
                for (int j = 0; j < 8; ++j) v[j] = (__bf16)acc[j][reg];
                *(bf16x8*)(&Y[((bl * 64 + q) * 8 + cs) * 8]) = v;
            }
        }
    }
    __syncthreads();  // the kernel's ONLY barrier

    // ---- stage-2: wave = (st = wid>>1, bh = wid&1). A = w2 (M=s), B = Y (N=b dup x4).
    // Lane keeps D[row = quad*4 + (m>>2)][col = m] => (b = bh*4+(m&3),
    // s = st*16 + quad*4 + (m>>2)); acc2[l] over all 64 l = one full 256-B granule.
    const int st   = wid >> 1;
    const int bh   = wid & 1;
    const int bcol = bh * 4 + (m & 3);
    const int sreg = m >> 2;
    const int srow = st * 16 + quad * 4 + sreg;

    const __bf16* w2base = w2b + (st * 16 + m) * 64 + quad * 8;
    const __bf16* Ybase  = Y + bcol * 64 * 64;   // Y[bcol][.][.]

    float acc2[64];
    #pragma unroll
    for (int l = 0; l < 64; ++l) {
        // A-frag: w2[l][s = st*16+m][r = h*32 + quad*8 + e]
        const __bf16* w2p = w2base + l * 4096;
        bf16x8 af0 = *(const bf16x8*)(w2p);
        bf16x8 af1 = *(const bf16x8*)(w2p + 32);
        // B-frag: Y[bcol][l][r = h*32 + quad*8 + e] (4-way col duplication broadcasts)
        const int cs0 = quad ^ (l & 7) ^ (bcol & 7);
        bf16x8 bf0 = *(const bf16x8*)(&Ybase[(l * 8 + cs0) * 8]);
        bf16x8 bf1 = *(const bf16x8*)(&Ybase[(l * 8 + (cs0 ^ 4)) * 8]);
        float4v c = {0.f, 0.f, 0.f, 0.f};
        c = __builtin_amdgcn_mfma_f32_16x16x32_bf16(af0, bf0, c, 0, 0, 0);
        c = __builtin_amdgcn_mfma_f32_16x16x32_bf16(af1, bf1, c, 0, 0, 0);
        acc2[l] = (sreg == 0) ? c[0] : (sreg == 1) ? c[1] : (sreg == 2) ? c[2] : c[3];
    }

    // ---- drain: 16 back-to-back dwordx4 stores per lane = one contiguous 256-B
    // granule out[b0+bcol][srow*64 .. +64]; same-wave adjacent instructions -> L2
    // merges to full lines, no partial-line eviction (r4-confirmed mechanism).
    float* dst = out + (long)(b0 + bcol) * 4096 + srow * 64;
    #pragma unroll
    for (int l4 = 0; l4 < 16; ++l4) {
        float4v v = { acc2[l4 * 4 + 0], acc2[l4 * 4 + 1],
                      acc2[l4 * 4 + 2], acc2[l4 * 4 + 3] };
        *(float4v*)(dst + l4 * 4) = v;
    }
}

extern "C" void kernel_launch(void* const* d_in, const int* in_sizes, int n_in,
                              void* d_out, int out_size, void* d_ws, size_t ws_size,
                              hipStream_t stream) {
    const float* x  = (const float*)d_in[0];
    const float* w1 = (const float*)d_in[1];
    const float* w2 = (const float*)d_in[2];
    float* out = (float*)d_out;
    __bf16* wb = (__bf16*)d_ws;   // w1b at [0, 262144), w2b at [262144, 524288)

    hipLaunchKernelGGL(cvt_weights, dim3(128), dim3(256), 0, stream, w1, w2, wb);
    hipLaunchKernelGGL(monarch_fused, dim3(8192 / 8), dim3(512), 65536, stream,
                       x, wb, wb + 262144, out);
}